// Round 15
// baseline (690.124 us; speedup 1.0000x reference)
//
#include <hip/hip_runtime.h>
#include <hip/hip_bf16.h>

// Fused 2-layer LSTM (H=32) + linear head, MI355X gfx950.
// r15: SELF-CONTAINED LAYER WAVES — the recurrence never crosses a wave.
// One wave computes a full layer (all 128 gate cols, 8 tiles) for 8 batch
// rows (MFMA M=16 with rows 8-15 duplicating 0-7; dup halves split the
// elementwise work so every lane owns exactly 4 real cells / 24 trans).
// h(t)->h(t+1): C-frag -> LDS -> A-frag within the SAME wave (in-order DS,
// lgkmcnt only) => NO s_barrier on the recurrent chain.
// WG = 2 waves: wave0 = L1, wave1 = L2 trailing WIN=8 steps via a 16-slot
// LDS h1 ring; ONE lgkm-only 2-wave barrier per 8 steps (65 total).
// 512 WGs x 2 waves = 1024 waves = 1/SIMD, 2 WGs/CU.
// Own-h reads pre-issued after own writes (same-wave in-order, race-free);
// L2 ring reads at step top, one full window old (r13 race lesson).
// h-side MFMA rounds first, input rounds second (read latency hides).
// Gates via mfma_f32_16x16x32_bf16, hi/lo bf16 split (~fp32 exact).

#define T_LEN 512
#define D_IN  28
#define WIN   8

typedef __attribute__((ext_vector_type(8))) short short8;   // 8 x bf16
typedef __attribute__((ext_vector_type(4))) float f32x4;
typedef __attribute__((ext_vector_type(4))) unsigned int u32x4;

#define K_SIG 1.4426950408889634f   // 1/ln2
#define K_TANH 2.8853900817779268f  // 2/ln2

// hi = bf16 truncation of x, lo = bf16 of exact residual (x - hi).
__device__ __forceinline__ void split_bf16(float x, short& hi, short& lo) {
  unsigned u = __float_as_uint(x);
  hi = (short)(u >> 16);
  float hf_ = __uint_as_float(u & 0xFFFF0000u);
  float lf = x - hf_;  // exact
  lo = (short)(__float_as_uint(lf) >> 16);
}

// dword = (top16(f1) << 16) | top16(f0), one v_perm_b32.
__device__ __forceinline__ unsigned pk_hi16(float f1, float f0) {
  return __builtin_amdgcn_perm(__float_as_uint(f1), __float_as_uint(f0),
                               0x07060302u);
}
__device__ __forceinline__ float trunc_bf(float f) {
  return __uint_as_float(__float_as_uint(f) & 0xFFFF0000u);
}

// Barrier draining LDS ops only (global x prefetch stays in flight).
__device__ __forceinline__ void lds_barrier() {
  asm volatile("s_waitcnt lgkmcnt(0)\n\ts_barrier" ::: "memory");
}

// B-operand tile (K=32 x N=16) of W (row-major G x ldk), gate rows
// t*16..t*16+15, k zero-padded past kval. Lane l: col=l&15, k=(l>>4)*8..+8.
__device__ __forceinline__ void load_wtile(const float* __restrict__ W, int ldk,
                                           int kval, int t, int lane,
                                           short8& hi, short8& lo) {
  int row = t * 16 + (lane & 15);
  int kb = (lane >> 4) * 8;
  const float* p = W + row * ldk + kb;
#pragma unroll
  for (int i = 0; i < 8; ++i) {
    float v = (kb + i < kval) ? p[i] : 0.0f;
    short h, l;
    split_bf16(v, h, l);
    hi[i] = h; lo[i] = l;
  }
}

#define MFMA(a, b, c) __builtin_amdgcn_mfma_f32_16x16x32_bf16(a, b, c, 0, 0, 0)

// Pack 8 floats (A0,A1) into hi/lo bf16 A-frags via v_perm.
__device__ __forceinline__ void pack_xfrag(const float4& A0, const float4& A1,
                                           short8& xh, short8& xl) {
  u32x4 xhu, xlu;
  xhu[0] = pk_hi16(A0.y, A0.x);
  xhu[1] = pk_hi16(A0.w, A0.z);
  xhu[2] = pk_hi16(A1.y, A1.x);
  xhu[3] = pk_hi16(A1.w, A1.z);
  float l0 = A0.x - trunc_bf(A0.x), l1 = A0.y - trunc_bf(A0.y);
  float l2 = A0.z - trunc_bf(A0.z), l3 = A0.w - trunc_bf(A0.w);
  float l4 = A1.x - trunc_bf(A1.x), l5 = A1.y - trunc_bf(A1.y);
  float l6 = A1.z - trunc_bf(A1.z), l7 = A1.w - trunc_bf(A1.w);
  xlu[0] = pk_hi16(l1, l0);
  xlu[1] = pk_hi16(l3, l2);
  xlu[2] = pk_hi16(l5, l4);
  xlu[3] = pk_hi16(l7, l6);
  xh = __builtin_bit_cast(short8, xhu);
  xl = __builtin_bit_cast(short8, xlu);
}

// 48 MFMAs: acc[t] = Wh-terms + input-terms, 6 rounds of 8 independent
// (same-acc reuse distance 8 => no dependent-issue stall). h-side FIRST
// (operands pre-read last step), input second (reads may still be in
// flight; their lgkm wait lands under rounds 1-3).
__device__ __forceinline__ void gates48(f32x4* acc,
    short8 hH, short8 hL, const short8* WhH, const short8* WhL,
    short8 inH, short8 inL, const short8* WxH, const short8* WxL) {
#pragma unroll
  for (int t = 0; t < 8; ++t) {
    f32x4 z = {0.f, 0.f, 0.f, 0.f};
    acc[t] = MFMA(hH, WhH[t], z);
  }
#pragma unroll
  for (int t = 0; t < 8; ++t) acc[t] = MFMA(hL, WhH[t], acc[t]);
#pragma unroll
  for (int t = 0; t < 8; ++t) acc[t] = MFMA(hH, WhL[t], acc[t]);
#pragma unroll
  for (int t = 0; t < 8; ++t) acc[t] = MFMA(inH, WxH[t], acc[t]);
#pragma unroll
  for (int t = 0; t < 8; ++t) acc[t] = MFMA(inL, WxH[t], acc[t]);
#pragma unroll
  for (int t = 0; t < 8; ++t) acc[t] = MFMA(inH, WxL[t], acc[t]);
}

// Cell update for this lane's 4 cells: (uh,ri) -> gate G = acc[2G+uh][r],
// r = (hi2?2:0)+ri (compile-time extracts selected by cndmask).
// Paired rcps: 20 exp2 + 4 rcp = 24 trans.
__device__ __forceinline__ void cell4(const f32x4* acc, bool hi2,
                                      float* c, float* h) {
  float gi[4], gf[4], gg[4], go[4];
#pragma unroll
  for (int uh = 0; uh < 2; ++uh) {
#pragma unroll
    for (int ri = 0; ri < 2; ++ri) {
      int j = uh * 2 + ri;
      gi[j] = hi2 ? acc[0 + uh][2 + ri] : acc[0 + uh][ri];
      gf[j] = hi2 ? acc[2 + uh][2 + ri] : acc[2 + uh][ri];
      gg[j] = hi2 ? acc[4 + uh][2 + ri] : acc[4 + uh][ri];
      go[j] = hi2 ? acc[6 + uh][2 + ri] : acc[6 + uh][ri];
    }
  }
  float ei[4], ef[4], eg[4], eo[4];
#pragma unroll
  for (int j = 0; j < 4; ++j) {
    ei[j] = __builtin_amdgcn_exp2f(gi[j] * -K_SIG);
    ef[j] = __builtin_amdgcn_exp2f(gf[j] * -K_SIG);
    eg[j] = __builtin_amdgcn_exp2f(gg[j] * K_TANH);
    eo[j] = __builtin_amdgcn_exp2f(go[j] * -K_SIG);
  }
  float num[4], D[4];
#pragma unroll
  for (int j = 0; j < 4; ++j) {
    float pig = (1.0f + ei[j]) * (1.0f + eg[j]);
    num[j] = c[j] * pig + (eg[j] - 1.0f) * (1.0f + ef[j]);
    D[j] = pig * (1.0f + ef[j]);
  }
  float R01 = __builtin_amdgcn_rcpf(D[0] * D[1]);
  float R23 = __builtin_amdgcn_rcpf(D[2] * D[3]);
  float cn[4];
  cn[0] = num[0] * D[1] * R01;
  cn[1] = num[1] * D[0] * R01;
  cn[2] = num[2] * D[3] * R23;
  cn[3] = num[3] * D[2] * R23;
  float ec[4], E[4];
#pragma unroll
  for (int j = 0; j < 4; ++j) ec[j] = __builtin_amdgcn_exp2f(cn[j] * K_TANH);
#pragma unroll
  for (int j = 0; j < 4; ++j) E[j] = (1.0f + eo[j]) * (1.0f + ec[j]);
  float S01 = __builtin_amdgcn_rcpf(E[0] * E[1]);
  float S23 = __builtin_amdgcn_rcpf(E[2] * E[3]);
  c[0] = cn[0]; h[0] = (ec[0] - 1.0f) * E[1] * S01;
  c[1] = cn[1]; h[1] = (ec[1] - 1.0f) * E[0] * S01;
  c[2] = cn[2]; h[2] = (ec[2] - 1.0f) * E[3] * S23;
  c[3] = cn[3]; h[3] = (ec[3] - 1.0f) * E[2] * S23;
}

// Store this lane's 4 cells (hi/lo bf16): cell (uh,ri) -> [bb+ri][cu+16uh].
__device__ __forceinline__ void store4(short (*dst)[8][40], const float* h,
                                       int bb, int cu) {
#pragma unroll
  for (int uh = 0; uh < 2; ++uh) {
#pragma unroll
    for (int ri = 0; ri < 2; ++ri) {
      int j = uh * 2 + ri;
      short hh_, ll_;
      split_bf16(h[j], hh_, ll_);
      dst[0][bb + ri][cu + 16 * uh] = hh_;
      dst[1][bb + ri][cu + 16 * uh] = ll_;
    }
  }
}

// One L1 step: pack x(s) from ring regs, refill for s+2, full-layer MFMA,
// cell update, publish h1(s) to ring slot; pre-read own h1(s) A-frag.
__device__ __forceinline__ void l1_step(
    float4& A0, float4& A1, const float* __restrict__ ld,
    const short8* WhH, const short8* WhL, const short8* WxH, const short8* WxL,
    short (*slot)[8][40], short8& hH, short8& hL, float* c, float* h,
    int brow, int g, int kb, int cu, bool hi2, int bb) {
  short8 xh, xl;
  pack_xfrag(A0, A1, xh, xl);
  A0 = *(const float4*)ld;           // 2-step flight, never waited young
  if (g < 3) A1 = *(const float4*)(ld + 4);
  f32x4 acc[8];
  gates48(acc, hH, hL, WhH, WhL, xh, xl, WxH, WxL);
  cell4(acc, hi2, c, h);
  store4(slot, h, bb, cu);
  // own-h pre-read: same wave, in-order DS after the writes -> race-free
  hH = *(const short8*)&slot[0][brow][kb];
  hL = *(const short8*)&slot[1][brow][kb];
}

// One L2 step: input = h1 from ring (one window old, post-barrier), own
// h2 from single buffer (same-wave in-order write->read).
__device__ __forceinline__ void l2_step(
    const short (*src)[8][40], short (*own)[8][40],
    const short8* WhH, const short8* WhL, const short8* WxH, const short8* WxL,
    short8& hH, short8& hL, float* c, float* h,
    int brow, int kb, int cu, bool hi2, int bb) {
  short8 inH = *(const short8*)&src[0][brow][kb];
  short8 inL = *(const short8*)&src[1][brow][kb];
  f32x4 acc[8];
  gates48(acc, hH, hL, WhH, WhL, inH, inL, WxH, WxL);
  cell4(acc, hi2, c, h);
  store4(own, h, bb, cu);
  hH = *(const short8*)&own[0][brow][kb];
  hL = *(const short8*)&own[1][brow][kb];
}

__global__ __launch_bounds__(128, 1) void lstm2_sw(
    const float* __restrict__ x, const float* __restrict__ wih0,
    const float* __restrict__ whh0, const float* __restrict__ wih1,
    const float* __restrict__ whh1, const float* __restrict__ wout,
    const float* __restrict__ bout, float* __restrict__ out) {
  __shared__ short ring[2 * WIN][2][8][40];  // h1 ring [slot][hi/lo][b][u]
  __shared__ short h2b[2][8][40];            // L2 own h2 (single buffer)
  __shared__ float hf[8][33];

  const int tid = threadIdx.x;
  const int lane = tid & 63;
  const int wv = tid >> 6;   // 0 = L1 wave, 1 = L2 wave
  const int b0 = blockIdx.x * 8;

  for (int i = tid; i < 2 * WIN * 2 * 8 * 40; i += 128) ((short*)ring)[i] = 0;
  for (int i = tid; i < 2 * 8 * 40; i += 128) ((short*)h2b)[i] = 0;

  const int lrow = lane & 15;   // A-frag row (8-15 duplicate 0-7)
  const int g = lane >> 4;      // k-group
  const int brow = lrow & 7;    // real batch row
  const int kb = g * 8;         // k/unit base (shorts for LDS, floats for x)
  const int cu = lrow;          // unit column base for this lane's cells
  const bool hi2 = (g >= 2);    // which C-row pair this lane finishes
  const int bb = (g * 4 + (hi2 ? 2 : 0)) & 7;  // first real batch row

  // ---- this wave's layer weights: 8 gate tiles x {Wx, Wh} hi/lo ----
  const float* Wx = wv ? wih1 : wih0;
  const float* Wh = wv ? whh1 : whh0;
  const int ldk = wv ? 32 : 28;
  short8 WxH[8], WxL[8], WhH[8], WhL[8];
#pragma unroll
  for (int t = 0; t < 8; ++t) {
    load_wtile(Wx, ldk, ldk, t, lane, WxH[t], WxL[t]);
    load_wtile(Wh, 32, 32, t, lane, WhH[t], WhL[t]);
  }

  float c[4] = {0, 0, 0, 0}, h[4] = {0, 0, 0, 0};
  short8 hH = {0, 0, 0, 0, 0, 0, 0, 0}, hL = hH;  // own-h A-frags (h(-1)=0)

  // static 2-deep x ring (L1 only): X0 = even steps, X1 = odd steps
  const float* xrow = x + (size_t)(b0 + brow) * T_LEN * D_IN + kb;
  float4 X00 = make_float4(0, 0, 0, 0), X01 = X00, X10 = X00, X11 = X00;
  if (wv == 0) {
    X00 = *(const float4*)(xrow);
    if (g < 3) X01 = *(const float4*)(xrow + 4);
    X10 = *(const float4*)(xrow + D_IN);
    if (g < 3) X11 = *(const float4*)(xrow + D_IN + 4);
  }

  __syncthreads();  // LDS zero-init visible

  // ---- main loop: 65 windows of 8 steps, ONE 2-wave barrier/window ----
  // Window w: L1 runs steps s=w*8+d writing ring slots (w&1)*8+d;
  //           L2 (w>=1) runs times u=(w-1)*8+d reading slots ((w&1)^1)*8+d
  //           (written in window w-1, published by that window's barrier).
  // Slot reuse: L1 rewrites slot j at step j+16 (window w+2) — one full
  // window after L2's read (window w+1), separated by a barrier.
#pragma unroll 1
  for (int w = 0; w < T_LEN / WIN + 1; ++w) {
    const int rw = (w & 1) * WIN;
    if (wv == 0) {
      if (w < T_LEN / WIN) {
        const int s8 = w * WIN;
#pragma unroll
        for (int dp = 0; dp < WIN / 2; ++dp) {
          {
            int s = s8 + 2 * dp;
            int t2 = (s + 2 < T_LEN) ? s + 2 : T_LEN - 1;
            l1_step(X00, X01, xrow + (size_t)t2 * D_IN, WhH, WhL, WxH, WxL,
                    ring[rw + 2 * dp], hH, hL, c, h, brow, g, kb, cu, hi2, bb);
          }
          {
            int s = s8 + 2 * dp + 1;
            int t2 = (s + 2 < T_LEN) ? s + 2 : T_LEN - 1;
            l1_step(X10, X11, xrow + (size_t)t2 * D_IN, WhH, WhL, WxH, WxL,
                    ring[rw + 2 * dp + 1], hH, hL, c, h, brow, g, kb, cu, hi2, bb);
          }
        }
      }
    } else {
      if (w >= 1) {
        const int rr = rw ^ WIN;
#pragma unroll
        for (int d = 0; d < WIN; ++d) {
          l2_step(ring[rr + d], h2b, WhH, WhL, WxH, WxL,
                  hH, hL, c, h, brow, kb, cu, hi2, bb);
        }
      }
    }
    lds_barrier();
  }

  // ---- epilogue: L2 wave holds h2(511); out = h2 @ wout^T + bout ----
  if (wv == 1) {
#pragma unroll
    for (int uh = 0; uh < 2; ++uh) {
#pragma unroll
      for (int ri = 0; ri < 2; ++ri) {
        hf[bb + ri][cu + 16 * uh] = h[uh * 2 + ri];
      }
    }
  }
  __syncthreads();

  for (int j = tid; j < 80; j += 128) {
    int row = j / 10, col = j % 10;
    float s = bout[col];
#pragma unroll
    for (int u = 0; u < 32; ++u) s += hf[row][u] * wout[col * 32 + u];
    out[(size_t)(b0 + row) * 10 + col] = s;
  }
}

extern "C" void kernel_launch(void* const* d_in, const int* in_sizes, int n_in,
                              void* d_out, int out_size, void* d_ws, size_t ws_size,
                              hipStream_t stream) {
  const float* x = (const float*)d_in[0];
  const float* wih0 = (const float*)d_in[1];
  const float* whh0 = (const float*)d_in[2];
  const float* wih1 = (const float*)d_in[3];
  const float* whh1 = (const float*)d_in[4];
  const float* wout = (const float*)d_in[5];
  const float* bout = (const float*)d_in[6];
  float* out = (float*)d_out;
  lstm2_sw<<<512, 128, 0, stream>>>(x, wih0, whh0, wih1, whh1, wout, bout, out);
}